// Round 3
// baseline (697.402 us; speedup 1.0000x reference)
//
#include <hip/hip_runtime.h>
#include <hip/hip_bf16.h>

#define HD 128
#define ED 16
#define TD 32

typedef __attribute__((ext_vector_type(8))) short short8;
typedef __attribute__((ext_vector_type(4))) float float4v;

__device__ __forceinline__ float siluf(float v){ return v * (1.0f / (1.0f + __expf(-v))); }

// bf16 pack/unpack helpers
__device__ __forceinline__ unsigned int bfbits(float x){          // RTNE
  unsigned int a = __float_as_uint(x);
  return (a + 0x7fffu + ((a >> 16) & 1u)) >> 16;
}
__device__ __forceinline__ unsigned int packbf(float lo, float hi){  // RTNE pair
  return (bfbits(lo) & 0xffffu) | (bfbits(hi) << 16);
}
// 1-op truncation pack via v_perm_b32: [lo.b2, lo.b3, hi.b2, hi.b3]
__device__ __forceinline__ unsigned int packtrunc(float lo, float hi){
  return __builtin_amdgcn_perm(__float_as_uint(hi), __float_as_uint(lo), 0x07060302u);
}
__device__ __forceinline__ unsigned short f2bt(float x){ return (unsigned short)(__float_as_uint(x) >> 16); }
__device__ __forceinline__ float unplo(unsigned int w){ return __uint_as_float(w << 16); }
__device__ __forceinline__ float unphi(unsigned int w){ return __uint_as_float(w & 0xffff0000u); }
__device__ __forceinline__ float b2f(unsigned short s){ return __uint_as_float(((unsigned int)s) << 16); }
__device__ __forceinline__ unsigned short f2b(float x){ return (unsigned short)bfbits(x); }

__device__ __forceinline__ void unp8(uint4 u, float* f){
  f[0]=unplo(u.x); f[1]=unphi(u.x); f[2]=unplo(u.y); f[3]=unphi(u.y);
  f[4]=unplo(u.z); f[5]=unphi(u.z); f[6]=unplo(u.w); f[7]=unphi(u.w);
}

__device__ __forceinline__ void atomAddF(float* p, float v){
  unsafeAtomicAdd(p, v);  // HW global_atomic_add_f32 on gfx950
}

// packed bf16 atomic add: one instruction adds 2 bf16 lanes-worth
__device__ __forceinline__ void atomAddBF2(unsigned short* p, unsigned int packed){
  asm volatile("global_atomic_pk_add_bf16 %0, %1, off"
               :: "v"((unsigned long long)(uintptr_t)p), "v"(packed) : "memory");
}

// ---------------------------------------------------------------------------
// Kernel 0: fp32 -> bf16 (RTNE) stream convert, 8 elems/thread-iter.
// ---------------------------------------------------------------------------
__global__ void __launch_bounds__(256) k_cvt(
    const float* __restrict__ src, unsigned short* __restrict__ dst, int n8)
{
  for (int i = blockIdx.x * 256 + threadIdx.x; i < n8; i += gridDim.x * 256){
    float4 v0 = *(const float4*)(src + (size_t)i * 8);
    float4 v1 = *(const float4*)(src + (size_t)i * 8 + 4);
    uint4 o;
    o.x = packbf(v0.x, v0.y); o.y = packbf(v0.z, v0.w);
    o.z = packbf(v1.x, v1.y); o.w = packbf(v1.z, v1.w);
    *(uint4*)(dst + (size_t)i * 8) = o;
  }
}

// ---------------------------------------------------------------------------
// Sort-by-dst preprocessing (counting sort): hist -> scan -> scatter.
// ---------------------------------------------------------------------------
__global__ void __launch_bounds__(256) k_hist(
    const int* __restrict__ ei, int* __restrict__ cnt, int E)
{
  for (int e = blockIdx.x * 256 + threadIdx.x; e < E; e += gridDim.x * 256)
    atomicAdd(&cnt[ei[E + e]], 1);
}

__global__ void __launch_bounds__(1024) k_scan(
    const int* __restrict__ cnt, int* __restrict__ off, int n)
{
  const int tid = threadIdx.x, lane = tid & 63, wv = tid >> 6;  // 16 waves
  __shared__ int wsum[16];
  __shared__ int carryS;
  if (tid == 0) carryS = 0;
  __syncthreads();
  const int CH = 1024 * 8;
  for (int base = 0; base < n; base += CH){
    const int idx0 = base + tid * 8;
    int v[8];
    #pragma unroll
    for (int j = 0; j < 8; ++j){ int i = idx0 + j; v[j] = (i < n) ? cnt[i] : 0; }
    #pragma unroll
    for (int j = 1; j < 8; ++j) v[j] += v[j - 1];   // local inclusive
    const int tot = v[7];
    int sc = tot;                                    // wave inclusive scan
    #pragma unroll
    for (int d = 1; d < 64; d <<= 1){ int t = __shfl_up(sc, d); if (lane >= d) sc += t; }
    if (lane == 63) wsum[wv] = sc;
    __syncthreads();
    if (tid < 16){
      int s = wsum[tid];
      #pragma unroll
      for (int d = 1; d < 16; d <<= 1){ int t = __shfl_up(s, d); if (tid >= d) s += t; }
      wsum[tid] = s;
    }
    __syncthreads();
    const int base_excl = carryS + (wv > 0 ? wsum[wv - 1] : 0) + (sc - tot);
    #pragma unroll
    for (int j = 0; j < 8; ++j){
      int i = idx0 + j;
      if (i < n) off[i] = base_excl + (j > 0 ? v[j - 1] : 0);
    }
    __syncthreads();
    if (tid == 0) carryS += wsum[15];
    __syncthreads();
  }
}

__global__ void __launch_bounds__(256) k_scatter(
    const int* __restrict__ ei, int* __restrict__ off,
    int* __restrict__ ss, int* __restrict__ ddv, int* __restrict__ perm, int E)
{
  for (int e = blockIdx.x * 256 + threadIdx.x; e < E; e += gridDim.x * 256){
    int s = ei[e], d = ei[E + e];
    int pos = atomicAdd(&off[d], 1);
    ss[pos] = s; ddv[pos] = d; perm[pos] = e;
  }
}

// ---------------------------------------------------------------------------
// Kernel 1: node-side first-layer GEMMs via MFMA; A from bf16 hb/tb.
// ---------------------------------------------------------------------------
__global__ void __launch_bounds__(256) k_pre2(
    const unsigned short* __restrict__ hb, const unsigned short* __restrict__ tb,
    const float* __restrict__ We_w1, const float* __restrict__ We_b1,
    const float* __restrict__ Wx_w1, const float* __restrict__ Wx_b1,
    const float* __restrict__ Wh_w1, const float* __restrict__ Wh_b1,
    unsigned short* __restrict__ Aes, unsigned short* __restrict__ Aed,
    unsigned short* __restrict__ Axs, unsigned short* __restrict__ Axd,
    unsigned short* __restrict__ zpre, int N)
{
  __shared__ unsigned short Wt[128 * 168];
  __shared__ unsigned short OutS[64 * 136];

  const int group = blockIdx.y;
  const float* Wsrc = (group <= 1) ? We_w1 : (group <= 3) ? Wx_w1 : Wh_w1;
  const float* bias = (group == 0) ? We_b1 : (group == 2) ? Wx_b1
                    : (group == 4) ? Wh_b1 : nullptr;
  unsigned short* out = (group == 0) ? Aes : (group == 1) ? Aed
                      : (group == 2) ? Axs : (group == 3) ? Axd : zpre;
  const int rowBase = (group == 1 || group == 3) ? 128 : 0;
  const int tBase   = (group == 0) ? 273 : (group == 2) ? 272 : -1;

  for (int i = threadIdx.x; i < 160 * 128; i += 256){
    int k = i >> 7, col = i & 127;
    float wv = 0.f;
    if (k < 128)      wv = Wsrc[(rowBase + k) * 128 + col];
    else if (tBase >= 0) wv = Wsrc[(tBase + (k - 128)) * 128 + col];
    Wt[col * 168 + k] = f2b(wv);
  }
  __syncthreads();

  const int lane = threadIdx.x & 63, w = threadIdx.x >> 6;
  const int m = lane & 15, q = lane >> 4;
  float bb[8];
  #pragma unroll
  for (int t = 0; t < 8; ++t) bb[t] = bias ? bias[t * 16 + m] : 0.f;

  const int ntiles = (N + 63) >> 6;
  for (int tile = blockIdx.x; tile < ntiles; tile += gridDim.x){
    const int n0 = tile << 6;
    const int n = min(n0 + w * 16 + m, N - 1);

    short8 a[5];
    #pragma unroll
    for (int step = 0; step < 4; ++step)
      a[step] = *(const short8*)(hb + (size_t)n * 128 + step * 32 + q * 8);
    a[4] = *(const short8*)(tb + (size_t)n * 32 + q * 8);

    float4v acc[8];
    #pragma unroll
    for (int t = 0; t < 8; ++t) acc[t] = (float4v){0.f, 0.f, 0.f, 0.f};
    #pragma unroll
    for (int step = 0; step < 5; ++step){
      #pragma unroll
      for (int t = 0; t < 8; ++t){
        short8 b = *(const short8*)(Wt + (size_t)(t * 16 + m) * 168 + step * 32 + q * 8);
        acc[t] = __builtin_amdgcn_mfma_f32_16x16x32_bf16(a[step], b, acc[t], 0, 0, 0);
      }
    }

    #pragma unroll
    for (int t = 0; t < 8; ++t)
      #pragma unroll
      for (int r = 0; r < 4; ++r)
        OutS[(w * 16 + q * 4 + r) * 136 + t * 16 + m] = f2b(acc[t][r] + bb[t]);
    __syncthreads();
    for (int i = threadIdx.x; i < 64 * 16; i += 256){
      int node = i >> 4, seg = i & 15;
      int nn = n0 + node;
      if (nn < N)
        *(uint4*)(out + (size_t)nn * 128 + seg * 8) =
            *(const uint4*)(OutS + node * 136 + seg * 8);
    }
    __syncthreads();
  }
}

// ---------------------------------------------------------------------------
// Kernel 2: message path over dst-SORTED edges. v3:
//  - amdgpu_waves_per_eu(4,4): LDS caps us at 4 waves/EU anyway; give the
//    register allocator the full 128-VGPR budget (was squeezing to 64).
//  - tail-B fragments in LDS (Btl) instead of 32 always-live VGPRs.
//  - 1-deep gather pipeline: next tile's gathers/ea/x issued before this
//    tile's MFMA + segmented emit; dist/dsh double-buffered.
// ---------------------------------------------------------------------------
__global__ void __launch_bounds__(512)
__attribute__((amdgpu_waves_per_eu(4, 4)))
k_edge_msg(
    const int* __restrict__ ss, const int* __restrict__ ddv,
    const int* __restrict__ perm,
    const float* __restrict__ x, const float* __restrict__ ea,
    const unsigned short* __restrict__ Aes, const unsigned short* __restrict__ Aed,
    const float* __restrict__ We_w1, const float* __restrict__ We_w2,
    const float* __restrict__ We_b2, const float* __restrict__ Watt_w,
    const float* __restrict__ Watt_b,
    unsigned short* __restrict__ msg_agg, int E)
{
  __shared__ unsigned short W2t[128 * 136];     // 34816 B, [col][k]
  __shared__ unsigned short Btl[128 * 32];      // 8192 B, tail B [col][k], k>=17 zero
  __shared__ unsigned short Ssh[8][16 * 136];   // 34816 B
  __shared__ float          distS[8][2][16];    // 1024 B (dbuf)
  __shared__ int            dsh[8][2][16];      // 1024 B (dbuf)
  // total 79872 B <= 81920 -> 2 blocks/CU (16 waves)

  const int tid = threadIdx.x;
  for (int i = tid; i < 128 * 128; i += 512){
    int col = i & 127, k = i >> 7;
    W2t[col * 136 + k] = f2b(We_w2[k * 128 + col]);
  }
  for (int i = tid; i < 128 * 32; i += 512){
    int col = i >> 5, k = i & 31;
    float wv = (k < 16) ? We_w1[(257 + k) * 128 + col]
             : (k == 16 ? We_w1[256 * 128 + col] : 0.f);
    Btl[col * 32 + k] = f2b(wv);
  }
  __syncthreads();

  const int lane = tid & 63, w = tid >> 6;
  const int m = lane & 15, q = lane >> 4;

  float web2[8], watt[8];
  #pragma unroll
  for (int t = 0; t < 8; ++t){
    web2[t] = We_b2[t * 16 + m];
    watt[t] = Watt_w[t * 16 + m];
  }
  const float attb = Watt_b[0];

  unsigned short* S = Ssh[w];

  const int tiles = (E + 15) >> 4;
  const int wid = blockIdx.x * 8 + w;
  const int nwv = gridDim.x * 8;

  // ---- pipeline state ----
  uint4 G[8];
  float4 EA0 = {0,0,0,0}, EA1 = {0,0,0,0};
  int sL = 0, dL = 0;
  int sN[4], dN[4], pmN = 0;

  // ---- prologue: prefetch tile wid fully; indices for wid+nwv ----
  {
    const int e0 = wid << 4;
    if (lane < 16){
      int eC = min(e0 + lane, E - 1);
      int s = ss[eC], d = ddv[eC];
      float dx = x[s * 3 + 0] - x[d * 3 + 0];
      float dy = x[s * 3 + 1] - x[d * 3 + 1];
      float dz = x[s * 3 + 2] - x[d * 3 + 2];
      distS[w][0][lane] = dx * dx + dy * dy + dz * dz;
      dsh[w][0][lane] = d;
    }
    int s0[4], d0[4];
    #pragma unroll
    for (int it = 0; it < 4; ++it){
      const int eC = min(e0 + q + 4 * it, E - 1);
      s0[it] = ss[eC]; d0[it] = ddv[eC];
    }
    #pragma unroll
    for (int it = 0; it < 4; ++it){
      G[2 * it]     = *(const uint4*)(Aes + (size_t)s0[it] * HD + m * 8);
      G[2 * it + 1] = *(const uint4*)(Aed + (size_t)d0[it] * HD + m * 8);
    }
    if (q < 2){
      const int pm0 = perm[min(e0 + m, E - 1)];
      EA0 = *(const float4*)(ea + (size_t)pm0 * ED + q * 8);
      EA1 = *(const float4*)(ea + (size_t)pm0 * ED + q * 8 + 4);
    }
    const int en0 = min(wid + nwv, tiles - 1) << 4;
    if (lane < 16){
      int eC = min(en0 + lane, E - 1);
      sL = ss[eC]; dL = ddv[eC];
    }
    #pragma unroll
    for (int it = 0; it < 4; ++it){
      const int eC = min(en0 + q + 4 * it, E - 1);
      sN[it] = ss[eC]; dN[it] = ddv[eC];
    }
    pmN = perm[min(en0 + m, E - 1)];
  }

  int buf = 0;
  for (int tb = wid; tb < tiles; tb += nwv){
    const int e0 = tb << 4;

    // (1) x loads for NEXT tile
    float xs0=0, xs1=0, xs2=0, xd0=0, xd1=0, xd2=0;
    if (lane < 16){
      xs0 = x[sL * 3 + 0]; xs1 = x[sL * 3 + 1]; xs2 = x[sL * 3 + 2];
      xd0 = x[dL * 3 + 0]; xd1 = x[dL * 3 + 1]; xd2 = x[dL * 3 + 2];
    }

    // (2) staging compute for CURRENT tile from prefetched G
    #pragma unroll
    for (int it = 0; it < 4; ++it){
      const int eg = q + 4 * it;
      float fa[8], fb[8];
      unp8(G[2 * it], fa); unp8(G[2 * it + 1], fb);
      union { short8 v; unsigned int u[4]; } sv;
      #pragma unroll
      for (int jj = 0; jj < 4; ++jj)
        sv.u[jj] = packtrunc(fa[2 * jj] + fb[2 * jj], fa[2 * jj + 1] + fb[2 * jj + 1]);
      *(short8*)(S + eg * 136 + m * 8) = sv.v;
    }

    // (3) tail A-frag for CURRENT: k<16 = ea, k==16 = dist
    union { short8 v; unsigned int u[4]; } at;
    at.u[0] = at.u[1] = at.u[2] = at.u[3] = 0u;
    if (q < 2){
      at.u[0] = packtrunc(EA0.x, EA0.y); at.u[1] = packtrunc(EA0.z, EA0.w);
      at.u[2] = packtrunc(EA1.x, EA1.y); at.u[3] = packtrunc(EA1.z, EA1.w);
    } else if (q == 2){
      at.u[0] = __float_as_uint(distS[w][buf][m]) >> 16;
    }

    // (4) ISSUE next tile's gathers + ea (consume sN/dN/pmN)
    #pragma unroll
    for (int it = 0; it < 4; ++it){
      G[2 * it]     = *(const uint4*)(Aes + (size_t)sN[it] * HD + m * 8);
      G[2 * it + 1] = *(const uint4*)(Aed + (size_t)dN[it] * HD + m * 8);
    }
    if (q < 2){
      EA0 = *(const float4*)(ea + (size_t)pmN * ED + q * 8);
      EA1 = *(const float4*)(ea + (size_t)pmN * ED + q * 8 + 4);
    }

    // (5) tail MFMA (B from LDS Btl), C init from staged sums; silu -> bf16
    #pragma unroll
    for (int t = 0; t < 8; ++t){
      float4v ci;
      #pragma unroll
      for (int r = 0; r < 4; ++r)
        ci[r] = b2f(S[(q * 4 + r) * 136 + t * 16 + m]);
      short8 b = *(const short8*)(Btl + (t * 16 + m) * 32 + q * 8);
      float4v o = __builtin_amdgcn_mfma_f32_16x16x32_bf16(at.v, b, ci, 0, 0, 0);
      #pragma unroll
      for (int r = 0; r < 4; ++r)
        S[(q * 4 + r) * 136 + t * 16 + m] = f2bt(siluf(o[r]));
    }

    // (6) layer-2 MFMA, B from shared W2t
    float4v c2[8];
    #pragma unroll
    for (int t = 0; t < 8; ++t) c2[t] = (float4v){0.f, 0.f, 0.f, 0.f};
    #pragma unroll
    for (int step = 0; step < 4; ++step){
      short8 a2 = *(const short8*)(S + m * 136 + step * 32 + q * 8);
      #pragma unroll
      for (int t = 0; t < 8; ++t){
        short8 b = *(const short8*)(W2t + (size_t)(t * 16 + m) * 136 + step * 32 + q * 8);
        c2[t] = __builtin_amdgcn_mfma_f32_16x16x32_bf16(a2, b, c2[t], 0, 0, 0);
      }
    }

    // (7) attention + write gated m-values (bf16) back into S
    #pragma unroll
    for (int r = 0; r < 4; ++r){
      float mp[8], p = 0.f;
      #pragma unroll
      for (int t = 0; t < 8; ++t){
        mp[t] = c2[t][r] + web2[t];
        p = fmaf(mp[t], watt[t], p);
      }
      p += __shfl_xor(p, 1); p += __shfl_xor(p, 2);
      p += __shfl_xor(p, 4); p += __shfl_xor(p, 8);
      float att = 1.f / (1.f + __expf(-(p + attb)));
      #pragma unroll
      for (int t = 0; t < 8; ++t)
        S[(q * 4 + r) * 136 + t * 16 + m] = f2bt(att * mp[t]);
    }

    // (8) dist/dsh for NEXT tile into buf^1 (consumes x loads from (1))
    if (lane < 16){
      float dx = xs0 - xd0, dy = xs1 - xd1, dz = xs2 - xd2;
      distS[w][buf ^ 1][lane] = dx * dx + dy * dy + dz * dz;
      dsh[w][buf ^ 1][lane] = dL;
    }

    // (9) indices for tile t+2 (issued BEFORE this tile's atomics)
    {
      const int en2 = min(tb + 2 * nwv, tiles - 1) << 4;
      if (lane < 16){
        int eC = min(en2 + lane, E - 1);
        sL = ss[eC]; dL = ddv[eC];
      }
      #pragma unroll
      for (int it = 0; it < 4; ++it){
        const int eC = min(en2 + q + 4 * it, E - 1);
        sN[it] = ss[eC]; dN[it] = ddv[eC];
      }
      pmN = perm[min(en2 + m, E - 1)];
    }

    // (10) segmented f32 reduction over sorted dsts; one pk atomic per run
    __builtin_amdgcn_sched_barrier(0);
    unsigned int vv[16]; int dvr[16];
    #pragma unroll
    for (int eg = 0; eg < 16; ++eg){
      vv[eg]  = *(const unsigned int*)(S + eg * 136 + lane * 2);
      dvr[eg] = dsh[w][buf][eg];
    }
    float a0 = 0.f, a1 = 0.f;
    int dp = dvr[0];
    #pragma unroll
    for (int eg = 0; eg < 16; ++eg){
      if (dvr[eg] != dp){                       // wave-uniform branch
        atomAddBF2(msg_agg + (size_t)dp * HD + lane * 2, packbf(a0, a1));
        a0 = a1 = 0.f; dp = dvr[eg];
      }
      if (e0 + eg < E){ a0 += unplo(vv[eg]); a1 += unphi(vv[eg]); }
    }
    atomAddBF2(msg_agg + (size_t)dp * HD + lane * 2, packbf(a0, a1));

    buf ^= 1;
  }
}

// ---------------------------------------------------------------------------
// Kernel 3: coord path over dst-SORTED edges. Same v3 treatment.
// ---------------------------------------------------------------------------
__global__ void __launch_bounds__(512)
__attribute__((amdgpu_waves_per_eu(4, 4)))
k_edge_coord(
    const int* __restrict__ ss, const int* __restrict__ ddv,
    const int* __restrict__ perm,
    const float* __restrict__ x, const float* __restrict__ ea,
    const unsigned short* __restrict__ Axs, const unsigned short* __restrict__ Axd,
    const float* __restrict__ Wx_w1, const float* __restrict__ Wx_w2,
    const float* __restrict__ Wx_b2, const float* __restrict__ Wx_w3,
    float* __restrict__ xout, int E)
{
  __shared__ unsigned short W2t[128 * 136];     // 34816 B
  __shared__ unsigned short Btl[128 * 16];      // 4096 B, tail B [col][k<16]
  __shared__ unsigned short Ssh[8][16 * 136];   // 34816 B
  __shared__ float          xaux[8][2][16 * 4]; // 4096 B (dbuf)
  __shared__ float          xcS[8][16 * 4];     // 2048 B
  __shared__ int            dsh[8][2][16];      // 1024 B (dbuf)
  // total 80896 B <= 81920 -> 2 blocks/CU

  const int tid = threadIdx.x;
  for (int i = tid; i < 128 * 128; i += 512){
    int col = i & 127, k = i >> 7;
    W2t[col * 136 + k] = f2b(Wx_w2[k * 128 + col]);
  }
  for (int i = tid; i < 128 * 16; i += 512){
    int col = i >> 4, k = i & 15;
    Btl[col * 16 + k] = f2b(Wx_w1[(256 + k) * 128 + col]);
  }
  __syncthreads();

  const int lane = tid & 63, w = tid >> 6;
  const int m = lane & 15, q = lane >> 4;

  float wxb2[8], w3v[8];
  #pragma unroll
  for (int t = 0; t < 8; ++t){
    wxb2[t] = Wx_b2[t * 16 + m];
    w3v[t]  = Wx_w3[t * 16 + m];
  }

  unsigned short* S = Ssh[w];
  float* xc = xcS[w];

  const int tiles = (E + 15) >> 4;
  const int wid = blockIdx.x * 8 + w;
  const int nwv = gridDim.x * 8;

  uint4 G[8];
  float4 EA0 = {0,0,0,0}, EA1 = {0,0,0,0};
  int sL = 0, dL = 0;
  int sN[4], dN[4], pmN = 0;

  // ---- prologue ----
  {
    const int e0 = wid << 4;
    if (lane < 16){
      int eC = min(e0 + lane, E - 1);
      int s = ss[eC], d = ddv[eC];
      float dx = x[s * 3 + 0] - x[d * 3 + 0];
      float dy = x[s * 3 + 1] - x[d * 3 + 1];
      float dz = x[s * 3 + 2] - x[d * 3 + 2];
      float dist = dx * dx + dy * dy + dz * dz;
      xaux[w][0][lane * 4 + 0] = dx;
      xaux[w][0][lane * 4 + 1] = dy;
      xaux[w][0][lane * 4 + 2] = dz;
      xaux[w][0][lane * 4 + 3] = 2.5f / (sqrtf(dist + 1e-8f) + 1.0f);
      dsh[w][0][lane] = d;
    }
    int s0[4], d0[4];
    #pragma unroll
    for (int it = 0; it < 4; ++it){
      const int eC = min(e0 + q + 4 * it, E - 1);
      s0[it] = ss[eC]; d0[it] = ddv[eC];
    }
    #pragma unroll
    for (int it = 0; it < 4; ++it){
      G[2 * it]     = *(const uint4*)(Axs + (size_t)s0[it] * HD + m * 8);
      G[2 * it + 1] = *(const uint4*)(Axd + (size_t)d0[it] * HD + m * 8);
    }
    if (q < 2){
      const int pm0 = perm[min(e0 + m, E - 1)];
      EA0 = *(const float4*)(ea + (size_t)pm0 * ED + q * 8);
      EA1 = *(const float4*)(ea + (size_t)pm0 * ED + q * 8 + 4);
    }
    const int en0 = min(wid + nwv, tiles - 1) << 4;
    if (lane < 16){
      int eC = min(en0 + lane, E - 1);
      sL = ss[eC]; dL = ddv[eC];
    }
    #pragma unroll
    for (int it = 0; it < 4; ++it){
      const int eC = min(en0 + q + 4 * it, E - 1);
      sN[it] = ss[eC]; dN[it] = ddv[eC];
    }
    pmN = perm[min(en0 + m, E - 1)];
  }

  int buf = 0;
  for (int tb = wid; tb < tiles; tb += nwv){
    const int e0 = tb << 4;

    // (1) x loads for NEXT tile
    float xs0=0, xs1=0, xs2=0, xd0=0, xd1=0, xd2=0;
    if (lane < 16){
      xs0 = x[sL * 3 + 0]; xs1 = x[sL * 3 + 1]; xs2 = x[sL * 3 + 2];
      xd0 = x[dL * 3 + 0]; xd1 = x[dL * 3 + 1]; xd2 = x[dL * 3 + 2];
    }

    // (2) staging compute for CURRENT tile
    #pragma unroll
    for (int it = 0; it < 4; ++it){
      const int eg = q + 4 * it;
      float fa[8], fb[8];
      unp8(G[2 * it], fa); unp8(G[2 * it + 1], fb);
      union { short8 v; unsigned int u[4]; } sv;
      #pragma unroll
      for (int jj = 0; jj < 4; ++jj)
        sv.u[jj] = packtrunc(fa[2 * jj] + fb[2 * jj], fa[2 * jj + 1] + fb[2 * jj + 1]);
      *(short8*)(S + eg * 136 + m * 8) = sv.v;
    }

    // (3) tail A-frag for CURRENT (ea only)
    union { short8 v; unsigned int u[4]; } at;
    at.u[0] = at.u[1] = at.u[2] = at.u[3] = 0u;
    if (q < 2){
      at.u[0] = packtrunc(EA0.x, EA0.y); at.u[1] = packtrunc(EA0.z, EA0.w);
      at.u[2] = packtrunc(EA1.x, EA1.y); at.u[3] = packtrunc(EA1.z, EA1.w);
    }

    // (4) ISSUE next tile's gathers + ea
    #pragma unroll
    for (int it = 0; it < 4; ++it){
      G[2 * it]     = *(const uint4*)(Axs + (size_t)sN[it] * HD + m * 8);
      G[2 * it + 1] = *(const uint4*)(Axd + (size_t)dN[it] * HD + m * 8);
    }
    if (q < 2){
      EA0 = *(const float4*)(ea + (size_t)pmN * ED + q * 8);
      EA1 = *(const float4*)(ea + (size_t)pmN * ED + q * 8 + 4);
    }

    // (5) tail MFMA (B from LDS Btl; zero for q>=2) + silu
    union { short8 v; unsigned int u[4]; } zb;
    zb.u[0] = zb.u[1] = zb.u[2] = zb.u[3] = 0u;
    #pragma unroll
    for (int t = 0; t < 8; ++t){
      float4v ci;
      #pragma unroll
      for (int r = 0; r < 4; ++r)
        ci[r] = b2f(S[(q * 4 + r) * 136 + t * 16 + m]);
      short8 b = (q < 2) ? *(const short8*)(Btl + (t * 16 + m) * 16 + q * 8) : zb.v;
      float4v o = __builtin_amdgcn_mfma_f32_16x16x32_bf16(at.v, b, ci, 0, 0, 0);
      #pragma unroll
      for (int r = 0; r < 4; ++r)
        S[(q * 4 + r) * 136 + t * 16 + m] = f2bt(siluf(o[r]));
    }

    // (6) layer-2 MFMA
    float4v c2[8];
    #pragma unroll
    for (int t = 0; t < 8; ++t) c2[t] = (float4v){0.f, 0.f, 0.f, 0.f};
    #pragma unroll
    for (int step = 0; step < 4; ++step){
      short8 a2 = *(const short8*)(S + m * 136 + step * 32 + q * 8);
      #pragma unroll
      for (int t = 0; t < 8; ++t){
        short8 b = *(const short8*)(W2t + (size_t)(t * 16 + m) * 136 + step * 32 + q * 8);
        c2[t] = __builtin_amdgcn_mfma_f32_16x16x32_bf16(a2, b, c2[t], 0, 0, 0);
      }
    }

    // (7) coord weight -> per-edge contributions into LDS
    const float* xa_cur = &xaux[w][buf][0];
    #pragma unroll
    for (int r = 0; r < 4; ++r){
      float p = 0.f;
      #pragma unroll
      for (int t = 0; t < 8; ++t)
        p = fmaf(siluf(c2[t][r] + wxb2[t]), w3v[t], p);
      p += __shfl_xor(p, 1); p += __shfl_xor(p, 2);
      p += __shfl_xor(p, 4); p += __shfl_xor(p, 8);
      const int eg = q * 4 + r;
      float sc = tanhf(p) * xa_cur[eg * 4 + 3];
      if (m < 3) xc[eg * 4 + m] = xa_cur[eg * 4 + m] * sc;
    }

    // (8) xaux/dsh for NEXT tile into buf^1
    if (lane < 16){
      float dx = xs0 - xd0, dy = xs1 - xd1, dz = xs2 - xd2;
      float dist = dx * dx + dy * dy + dz * dz;
      xaux[w][buf ^ 1][lane * 4 + 0] = dx;
      xaux[w][buf ^ 1][lane * 4 + 1] = dy;
      xaux[w][buf ^ 1][lane * 4 + 2] = dz;
      xaux[w][buf ^ 1][lane * 4 + 3] = 2.5f / (sqrtf(dist + 1e-8f) + 1.0f);
      dsh[w][buf ^ 1][lane] = dL;
    }

    // (9) indices for tile t+2
    {
      const int en2 = min(tb + 2 * nwv, tiles - 1) << 4;
      if (lane < 16){
        int eC = min(en2 + lane, E - 1);
        sL = ss[eC]; dL = ddv[eC];
      }
      #pragma unroll
      for (int it = 0; it < 4; ++it){
        const int eC = min(en2 + q + 4 * it, E - 1);
        sN[it] = ss[eC]; dN[it] = ddv[eC];
      }
      pmN = perm[min(en2 + m, E - 1)];
    }

    // (10) segmented emit: lanes 0..2, one f32 atomic per same-dst run
    __builtin_amdgcn_sched_barrier(0);
    if (lane < 3){
      const int* dI = dsh[w][buf];
      int dp = dI[0]; float acc = 0.f;
      #pragma unroll
      for (int eg = 0; eg < 16; ++eg){
        int dc = dI[eg];
        if (dc != dp){
          atomAddF(xout + (size_t)dp * 3 + lane, acc);
          acc = 0.f; dp = dc;
        }
        if (e0 + eg < E) acc += xc[eg * 4 + lane];
      }
      atomAddF(xout + (size_t)dp * 3 + lane, acc);
    }

    buf ^= 1;
  }
}

// ---------------------------------------------------------------------------
// Kernel 4: z2 = bf16( silu( zpre + msg @ Wh_w1[128:256] ) ) — msg bf16.
// ---------------------------------------------------------------------------
__global__ void __launch_bounds__(256) k_h1b2(
    const unsigned short* __restrict__ msg, const unsigned short* __restrict__ zpre,
    const float* __restrict__ Wh_w1, unsigned short* __restrict__ z2, int N)
{
  __shared__ unsigned short Wt[128 * 136];
  __shared__ unsigned short OutS[64 * 136];

  for (int i = threadIdx.x; i < 128 * 128; i += 256){
    int k = i >> 7, col = i & 127;
    Wt[col * 136 + k] = f2b(Wh_w1[(128 + k) * 128 + col]);
  }
  __syncthreads();

  const int lane = threadIdx.x & 63, w = threadIdx.x >> 6;
  const int m = lane & 15, q = lane >> 4;

  const int ntiles = (N + 63) >> 6;
  for (int tile = blockIdx.x; tile < ntiles; tile += gridDim.x){
    const int n0 = tile << 6;
    const int n = min(n0 + w * 16 + m, N - 1);

    short8 a[4];
    #pragma unroll
    for (int step = 0; step < 4; ++step)
      a[step] = *(const short8*)(msg + (size_t)n * 128 + step * 32 + q * 8);

    float4v acc[8];
    #pragma unroll
    for (int t = 0; t < 8; ++t) acc[t] = (float4v){0.f, 0.f, 0.f, 0.f};
    #pragma unroll
    for (int step = 0; step < 4; ++step){
      #pragma unroll
      for (int t = 0; t < 8; ++t){
        short8 b = *(const short8*)(Wt + (size_t)(t * 16 + m) * 136 + step * 32 + q * 8);
        acc[t] = __builtin_amdgcn_mfma_f32_16x16x32_bf16(a[step], b, acc[t], 0, 0, 0);
      }
    }

    #pragma unroll
    for (int t = 0; t < 8; ++t)
      #pragma unroll
      for (int r = 0; r < 4; ++r)
        OutS[(w * 16 + q * 4 + r) * 136 + t * 16 + m] = f2b(acc[t][r]);
    __syncthreads();
    for (int i = threadIdx.x; i < 64 * 16; i += 256){
      int node = i >> 4, seg = i & 15;
      int nn = n0 + node;
      if (nn < N){
        uint4 dv = *(const uint4*)(OutS + node * 136 + seg * 8);
        uint4 zv = *(const uint4*)(zpre + (size_t)nn * 128 + seg * 8);
        float fd[8], fz[8];
        unp8(dv, fd); unp8(zv, fz);
        uint4 ov;
        ov.x = packbf(siluf(fz[0] + fd[0]), siluf(fz[1] + fd[1]));
        ov.y = packbf(siluf(fz[2] + fd[2]), siluf(fz[3] + fd[3]));
        ov.z = packbf(siluf(fz[4] + fd[4]), siluf(fz[5] + fd[5]));
        ov.w = packbf(siluf(fz[6] + fd[6]), siluf(fz[7] + fd[7]));
        *(uint4*)(z2 + (size_t)nn * 128 + seg * 8) = ov;
      }
    }
    __syncthreads();
  }
}

// ---------------------------------------------------------------------------
// Kernel 5: hout = h + z2 @ Wh_w2 + Wh_b2
// ---------------------------------------------------------------------------
__global__ void __launch_bounds__(256) k_h22(
    const float* __restrict__ h, const unsigned short* __restrict__ z2,
    const float* __restrict__ Wh_w2, const float* __restrict__ Wh_b2,
    float* __restrict__ hout, int N)
{
  __shared__ unsigned short Wt[128 * 136];
  __shared__ float OutSf[64 * 132];

  for (int i = threadIdx.x; i < 128 * 128; i += 256){
    int k = i >> 7, col = i & 127;
    Wt[col * 136 + k] = f2b(Wh_w2[k * 128 + col]);
  }
  __syncthreads();

  const int lane = threadIdx.x & 63, w = threadIdx.x >> 6;
  const int m = lane & 15, q = lane >> 4;
  float bb[8];
  #pragma unroll
  for (int t = 0; t < 8; ++t) bb[t] = Wh_b2[t * 16 + m];

  const int ntiles = (N + 63) >> 6;
  for (int tile = blockIdx.x; tile < ntiles; tile += gridDim.x){
    const int n0 = tile << 6;
    const int n = min(n0 + w * 16 + m, N - 1);

    short8 a[4];
    #pragma unroll
    for (int step = 0; step < 4; ++step)
      a[step] = *(const short8*)(z2 + (size_t)n * 128 + step * 32 + q * 8);

    float4v acc[8];
    #pragma unroll
    for (int t = 0; t < 8; ++t) acc[t] = (float4v){0.f, 0.f, 0.f, 0.f};
    #pragma unroll
    for (int step = 0; step < 4; ++step){
      #pragma unroll
      for (int t = 0; t < 8; ++t){
        short8 b = *(const short8*)(Wt + (size_t)(t * 16 + m) * 136 + step * 32 + q * 8);
        acc[t] = __builtin_amdgcn_mfma_f32_16x16x32_bf16(a[step], b, acc[t], 0, 0, 0);
      }
    }

    #pragma unroll
    for (int t = 0; t < 8; ++t)
      #pragma unroll
      for (int r = 0; r < 4; ++r)
        OutSf[(w * 16 + q * 4 + r) * 132 + t * 16 + m] = acc[t][r] + bb[t];
    __syncthreads();
    for (int i = threadIdx.x; i < 64 * 32; i += 256){
      int node = i >> 5, seg = i & 31;
      int nn = n0 + node;
      if (nn < N){
        float4 dv = *(const float4*)(OutSf + node * 132 + seg * 4);
        float4 hv = *(const float4*)(h + (size_t)nn * 128 + seg * 4);
        float4 ov = {hv.x + dv.x, hv.y + dv.y, hv.z + dv.z, hv.w + dv.w};
        *(float4*)(hout + (size_t)nn * 128 + seg * 4) = ov;
      }
    }
    __syncthreads();
  }
}

extern "C" void kernel_launch(void* const* d_in, const int* in_sizes, int n_in,
                              void* d_out, int out_size, void* d_ws, size_t ws_size,
                              hipStream_t stream)
{
  const float* h      = (const float*)d_in[0];
  const float* x      = (const float*)d_in[1];
  const int*   ei     = (const int*)  d_in[2];
  const float* ea     = (const float*)d_in[3];
  const float* t_emb  = (const float*)d_in[4];
  const float* We_w1  = (const float*)d_in[5];
  const float* We_b1  = (const float*)d_in[6];
  const float* We_w2  = (const float*)d_in[7];
  const float* We_b2  = (const float*)d_in[8];
  const float* Watt_w = (const float*)d_in[9];
  const float* Watt_b = (const float*)d_in[10];
  const float* Wx_w1  = (const float*)d_in[11];
  const float* Wx_b1  = (const float*)d_in[12];
  const float* Wx_w2  = (const float*)d_in[13];
  const float* Wx_b2  = (const float*)d_in[14];
  const float* Wx_w3  = (const float*)d_in[15];
  const float* Wh_w1  = (const float*)d_in[16];
  const float* Wh_b1  = (const float*)d_in[17];
  const float* Wh_w2  = (const float*)d_in[18];
  const float* Wh_b2  = (const float*)d_in[19];

  const int N = in_sizes[0] / HD;
  const int E = in_sizes[2] / 2;

  char* ws = (char*)d_ws;
  unsigned short* Aes  = (unsigned short*)ws;  ws += (size_t)N * HD * 2;
  unsigned short* Aed  = (unsigned short*)ws;  ws += (size_t)N * HD * 2;
  unsigned short* Axs  = (unsigned short*)ws;  ws += (size_t)N * HD * 2;
  unsigned short* Axd  = (unsigned short*)ws;  ws += (size_t)N * HD * 2;
  unsigned short* zpre = (unsigned short*)ws;  ws += (size_t)N * HD * 2;
  unsigned short* z2   = (unsigned short*)ws;  ws += (size_t)N * HD * 2;
  unsigned short* msg_agg = (unsigned short*)ws; ws += (size_t)N * HD * 2;
  unsigned short* hb   = (unsigned short*)ws;  ws += (size_t)N * HD * 2;
  unsigned short* tb   = (unsigned short*)ws;  ws += (size_t)N * TD * 2;

  // Reuse hb (12.8MB) for sorted-edge arrays (7.2MB) AFTER k_pre2 consumed it;
  // reuse tb (3.2MB) for cnt/off (0.4MB). Stream order guarantees safety.
  int* ss_   = (int*)hb;
  int* ddv_  = ss_ + E;
  int* perm_ = ddv_ + E;
  int* cnt_  = (int*)tb;
  int* off_  = cnt_ + N;

  float* hout = (float*)d_out;
  float* xout = hout + (size_t)N * HD;

  hipMemsetAsync(msg_agg, 0, (size_t)N * HD * 2, stream);
  hipMemcpyAsync(xout, x, (size_t)N * 3 * 4, hipMemcpyDeviceToDevice, stream);

  k_cvt<<<400, 256, 0, stream>>>(h, hb, N * (HD / 8));
  k_cvt<<<100, 256, 0, stream>>>(t_emb, tb, N * (TD / 8));

  dim3 gP(192, 5);
  k_pre2<<<gP, 256, 0, stream>>>(hb, tb, We_w1, We_b1, Wx_w1, Wx_b1,
                                 Wh_w1, Wh_b1, Aes, Aed, Axs, Axd, zpre, N);

  // counting sort by dst (after k_pre2: hb/tb regions are free)
  hipMemsetAsync(cnt_, 0, (size_t)N * 4, stream);
  k_hist<<<512, 256, 0, stream>>>(ei, cnt_, E);
  k_scan<<<1, 1024, 0, stream>>>(cnt_, off_, N);
  k_scatter<<<512, 256, 0, stream>>>(ei, off_, ss_, ddv_, perm_, E);

  k_edge_msg<<<512, 512, 0, stream>>>(ss_, ddv_, perm_, x, ea, Aes, Aed,
                                      We_w1, We_w2, We_b2, Watt_w, Watt_b,
                                      msg_agg, E);
  k_edge_coord<<<512, 512, 0, stream>>>(ss_, ddv_, perm_, x, ea, Axs, Axd,
                                        Wx_w1, Wx_w2, Wx_b2, Wx_w3, xout, E);
  k_h1b2<<<512, 256, 0, stream>>>(msg_agg, zpre, Wh_w1, z2, N);
  k_h22<<<512, 256, 0, stream>>>(h, z2, Wh_w2, Wh_b2, hout, N);
}

// Round 4
// 668.118 us; speedup vs baseline: 1.0438x; 1.0438x over previous
//
#include <hip/hip_runtime.h>
#include <hip/hip_bf16.h>

#define HD 128
#define ED 16
#define TD 32

typedef __attribute__((ext_vector_type(8))) short short8;
typedef __attribute__((ext_vector_type(4))) float float4v;

__device__ __forceinline__ float siluf(float v){ return v * (1.0f / (1.0f + __expf(-v))); }

// bf16 pack/unpack helpers
__device__ __forceinline__ unsigned int bfbits(float x){          // RTNE
  unsigned int a = __float_as_uint(x);
  return (a + 0x7fffu + ((a >> 16) & 1u)) >> 16;
}
__device__ __forceinline__ unsigned int packbf(float lo, float hi){  // RTNE pair
  return (bfbits(lo) & 0xffffu) | (bfbits(hi) << 16);
}
// 1-op truncation pack via v_perm_b32: [lo.b2, lo.b3, hi.b2, hi.b3]
__device__ __forceinline__ unsigned int packtrunc(float lo, float hi){
  return __builtin_amdgcn_perm(__float_as_uint(hi), __float_as_uint(lo), 0x07060302u);
}
__device__ __forceinline__ unsigned short f2bt(float x){ return (unsigned short)(__float_as_uint(x) >> 16); }
__device__ __forceinline__ float unplo(unsigned int w){ return __uint_as_float(w << 16); }
__device__ __forceinline__ float unphi(unsigned int w){ return __uint_as_float(w & 0xffff0000u); }
__device__ __forceinline__ float b2f(unsigned short s){ return __uint_as_float(((unsigned int)s) << 16); }
__device__ __forceinline__ unsigned short f2b(float x){ return (unsigned short)bfbits(x); }

__device__ __forceinline__ void unp8(uint4 u, float* f){
  f[0]=unplo(u.x); f[1]=unphi(u.x); f[2]=unplo(u.y); f[3]=unphi(u.y);
  f[4]=unplo(u.z); f[5]=unphi(u.z); f[6]=unplo(u.w); f[7]=unphi(u.w);
}

__device__ __forceinline__ void atomAddF(float* p, float v){
  unsafeAtomicAdd(p, v);  // HW global_atomic_add_f32 on gfx950
}

// packed bf16 atomic add: one instruction adds 2 bf16 lanes-worth
__device__ __forceinline__ void atomAddBF2(unsigned short* p, unsigned int packed){
  asm volatile("global_atomic_pk_add_bf16 %0, %1, off"
               :: "v"((unsigned long long)(uintptr_t)p), "v"(packed) : "memory");
}

// ---------------------------------------------------------------------------
// Kernel 0: fp32 -> bf16 (RTNE) stream convert, 8 elems/thread-iter.
// ---------------------------------------------------------------------------
__global__ void __launch_bounds__(256) k_cvt(
    const float* __restrict__ src, unsigned short* __restrict__ dst, int n8)
{
  for (int i = blockIdx.x * 256 + threadIdx.x; i < n8; i += gridDim.x * 256){
    float4 v0 = *(const float4*)(src + (size_t)i * 8);
    float4 v1 = *(const float4*)(src + (size_t)i * 8 + 4);
    uint4 o;
    o.x = packbf(v0.x, v0.y); o.y = packbf(v0.z, v0.w);
    o.z = packbf(v1.x, v1.y); o.w = packbf(v1.z, v1.w);
    *(uint4*)(dst + (size_t)i * 8) = o;
  }
}

// ---------------------------------------------------------------------------
// Sort-by-dst preprocessing (counting sort): hist -> scan -> scatter.
// ---------------------------------------------------------------------------
__global__ void __launch_bounds__(256) k_hist(
    const int* __restrict__ ei, int* __restrict__ cnt, int E)
{
  for (int e = blockIdx.x * 256 + threadIdx.x; e < E; e += gridDim.x * 256)
    atomicAdd(&cnt[ei[E + e]], 1);
}

__global__ void __launch_bounds__(1024) k_scan(
    const int* __restrict__ cnt, int* __restrict__ off, int n)
{
  const int tid = threadIdx.x, lane = tid & 63, wv = tid >> 6;  // 16 waves
  __shared__ int wsum[16];
  __shared__ int carryS;
  if (tid == 0) carryS = 0;
  __syncthreads();
  const int CH = 1024 * 8;
  for (int base = 0; base < n; base += CH){
    const int idx0 = base + tid * 8;
    int v[8];
    #pragma unroll
    for (int j = 0; j < 8; ++j){ int i = idx0 + j; v[j] = (i < n) ? cnt[i] : 0; }
    #pragma unroll
    for (int j = 1; j < 8; ++j) v[j] += v[j - 1];   // local inclusive
    const int tot = v[7];
    int sc = tot;                                    // wave inclusive scan
    #pragma unroll
    for (int d = 1; d < 64; d <<= 1){ int t = __shfl_up(sc, d); if (lane >= d) sc += t; }
    if (lane == 63) wsum[wv] = sc;
    __syncthreads();
    if (tid < 16){
      int s = wsum[tid];
      #pragma unroll
      for (int d = 1; d < 16; d <<= 1){ int t = __shfl_up(s, d); if (tid >= d) s += t; }
      wsum[tid] = s;
    }
    __syncthreads();
    const int base_excl = carryS + (wv > 0 ? wsum[wv - 1] : 0) + (sc - tot);
    #pragma unroll
    for (int j = 0; j < 8; ++j){
      int i = idx0 + j;
      if (i < n) off[i] = base_excl + (j > 0 ? v[j - 1] : 0);
    }
    __syncthreads();
    if (tid == 0) carryS += wsum[15];
    __syncthreads();
  }
}

__global__ void __launch_bounds__(256) k_scatter(
    const int* __restrict__ ei, int* __restrict__ off,
    int* __restrict__ ss, int* __restrict__ ddv, int* __restrict__ perm, int E)
{
  for (int e = blockIdx.x * 256 + threadIdx.x; e < E; e += gridDim.x * 256){
    int s = ei[e], d = ei[E + e];
    int pos = atomicAdd(&off[d], 1);
    ss[pos] = s; ddv[pos] = d; perm[pos] = e;
  }
}

// ---------------------------------------------------------------------------
// Kernel 1: node-side first-layer GEMMs via MFMA; A from bf16 hb/tb.
// ---------------------------------------------------------------------------
__global__ void __launch_bounds__(256) k_pre2(
    const unsigned short* __restrict__ hb, const unsigned short* __restrict__ tb,
    const float* __restrict__ We_w1, const float* __restrict__ We_b1,
    const float* __restrict__ Wx_w1, const float* __restrict__ Wx_b1,
    const float* __restrict__ Wh_w1, const float* __restrict__ Wh_b1,
    unsigned short* __restrict__ Aes, unsigned short* __restrict__ Aed,
    unsigned short* __restrict__ Axs, unsigned short* __restrict__ Axd,
    unsigned short* __restrict__ zpre, int N)
{
  __shared__ unsigned short Wt[128 * 168];
  __shared__ unsigned short OutS[64 * 136];

  const int group = blockIdx.y;
  const float* Wsrc = (group <= 1) ? We_w1 : (group <= 3) ? Wx_w1 : Wh_w1;
  const float* bias = (group == 0) ? We_b1 : (group == 2) ? Wx_b1
                    : (group == 4) ? Wh_b1 : nullptr;
  unsigned short* out = (group == 0) ? Aes : (group == 1) ? Aed
                      : (group == 2) ? Axs : (group == 3) ? Axd : zpre;
  const int rowBase = (group == 1 || group == 3) ? 128 : 0;
  const int tBase   = (group == 0) ? 273 : (group == 2) ? 272 : -1;

  for (int i = threadIdx.x; i < 160 * 128; i += 256){
    int k = i >> 7, col = i & 127;
    float wv = 0.f;
    if (k < 128)      wv = Wsrc[(rowBase + k) * 128 + col];
    else if (tBase >= 0) wv = Wsrc[(tBase + (k - 128)) * 128 + col];
    Wt[col * 168 + k] = f2b(wv);
  }
  __syncthreads();

  const int lane = threadIdx.x & 63, w = threadIdx.x >> 6;
  const int m = lane & 15, q = lane >> 4;
  float bb[8];
  #pragma unroll
  for (int t = 0; t < 8; ++t) bb[t] = bias ? bias[t * 16 + m] : 0.f;

  const int ntiles = (N + 63) >> 6;
  for (int tile = blockIdx.x; tile < ntiles; tile += gridDim.x){
    const int n0 = tile << 6;
    const int n = min(n0 + w * 16 + m, N - 1);

    short8 a[5];
    #pragma unroll
    for (int step = 0; step < 4; ++step)
      a[step] = *(const short8*)(hb + (size_t)n * 128 + step * 32 + q * 8);
    a[4] = *(const short8*)(tb + (size_t)n * 32 + q * 8);

    float4v acc[8];
    #pragma unroll
    for (int t = 0; t < 8; ++t) acc[t] = (float4v){0.f, 0.f, 0.f, 0.f};
    #pragma unroll
    for (int step = 0; step < 5; ++step){
      #pragma unroll
      for (int t = 0; t < 8; ++t){
        short8 b = *(const short8*)(Wt + (size_t)(t * 16 + m) * 168 + step * 32 + q * 8);
        acc[t] = __builtin_amdgcn_mfma_f32_16x16x32_bf16(a[step], b, acc[t], 0, 0, 0);
      }
    }

    #pragma unroll
    for (int t = 0; t < 8; ++t)
      #pragma unroll
      for (int r = 0; r < 4; ++r)
        OutS[(w * 16 + q * 4 + r) * 136 + t * 16 + m] = f2b(acc[t][r] + bb[t]);
    __syncthreads();
    for (int i = threadIdx.x; i < 64 * 16; i += 256){
      int node = i >> 4, seg = i & 15;
      int nn = n0 + node;
      if (nn < N)
        *(uint4*)(out + (size_t)nn * 128 + seg * 8) =
            *(const uint4*)(OutS + node * 136 + seg * 8);
    }
    __syncthreads();
  }
}

// ---------------------------------------------------------------------------
// Kernel 2: message path over dst-SORTED edges. v4: swapped-operand MFMA
// (D^T = W^T · in^T): S layout unchanged [edge][n]; C/D lane map becomes
// col=edge, row=n -> contiguous b64 LDS round-trips, 1 sigmoid/lane,
// 2-shfl attention reduce. __launch_bounds__(512,4) -> 128-VGPR budget so
// the 1-deep gather pipeline doesn't spill.
// ---------------------------------------------------------------------------
__global__ void __launch_bounds__(512, 4) k_edge_msg(
    const int* __restrict__ ss, const int* __restrict__ ddv,
    const int* __restrict__ perm,
    const float* __restrict__ x, const float* __restrict__ ea,
    const unsigned short* __restrict__ Aes, const unsigned short* __restrict__ Aed,
    const float* __restrict__ We_w1, const float* __restrict__ We_w2,
    const float* __restrict__ We_b2, const float* __restrict__ Watt_w,
    const float* __restrict__ Watt_b,
    unsigned short* __restrict__ msg_agg, int E)
{
  __shared__ __align__(16) unsigned short W2t[128 * 136];   // 34816 B  [n][k]
  __shared__ __align__(16) unsigned short Btl[128 * 24];    // 6144 B   [n][k<24]
  __shared__ __align__(16) unsigned short Ssh[8][16 * 136]; // 34816 B  [edge][n]
  __shared__ __align__(16) float b2l[128];                  // 512 B
  __shared__ __align__(16) float wal[128];                  // 512 B
  __shared__ float distS[8][16];                            // 512 B
  __shared__ int   dsh[8][16];                              // 512 B
  // total 77824 B -> 2 blocks/CU (16 waves)

  const int tid = threadIdx.x;
  for (int i = tid; i < 128 * 128; i += 512){
    int col = i & 127, k = i >> 7;
    W2t[col * 136 + k] = f2b(We_w2[k * 128 + col]);
  }
  for (int i = tid; i < 128 * 24; i += 512){
    int col = i / 24, k = i % 24;
    float wv = (k < 16) ? We_w1[(257 + k) * 128 + col]
             : (k == 16 ? We_w1[256 * 128 + col] : 0.f);
    Btl[col * 24 + k] = f2b(wv);
  }
  for (int i = tid; i < 128; i += 512){
    b2l[i] = We_b2[i];
    wal[i] = Watt_w[i];
  }
  __syncthreads();

  const int lane = tid & 63, w = tid >> 6;
  const int m = lane & 15, q = lane >> 4;
  const float attb = Watt_b[0];

  unsigned short* S = Ssh[w];

  const int tiles = (E + 15) >> 4;
  const int wid = blockIdx.x * 8 + w;
  const int nwv = gridDim.x * 8;

  // ---- pipeline state: gathers one tile ahead; staging indices one beyond ----
  uint4 G[8];
  float4 EA0 = {0,0,0,0}, EA1 = {0,0,0,0};
  int sN[4], dN[4], pmN = 0;

  {
    const int e0 = wid << 4;
    int s0[4], d0[4];
    #pragma unroll
    for (int it = 0; it < 4; ++it){
      const int eC = min(e0 + q + 4 * it, E - 1);
      s0[it] = ss[eC]; d0[it] = ddv[eC];
    }
    #pragma unroll
    for (int it = 0; it < 4; ++it){
      G[2 * it]     = *(const uint4*)(Aes + (size_t)s0[it] * HD + m * 8);
      G[2 * it + 1] = *(const uint4*)(Aed + (size_t)d0[it] * HD + m * 8);
    }
    if (q < 2){
      const int pm0 = perm[min(e0 + m, E - 1)];
      EA0 = *(const float4*)(ea + (size_t)pm0 * ED + q * 8);
      EA1 = *(const float4*)(ea + (size_t)pm0 * ED + q * 8 + 4);
    }
    const int en0 = min(wid + nwv, tiles - 1) << 4;
    #pragma unroll
    for (int it = 0; it < 4; ++it){
      const int eC = min(en0 + q + 4 * it, E - 1);
      sN[it] = ss[eC]; dN[it] = ddv[eC];
    }
    pmN = perm[min(en0 + m, E - 1)];
  }

  for (int tb = wid; tb < tiles; tb += nwv){
    const int e0 = tb << 4;

    // (A) per-edge scalars for CURRENT tile (lanes 0..15; seq loads, L1/L2-hot)
    if (lane < 16){
      int eC = min(e0 + lane, E - 1);
      int s = ss[eC], d = ddv[eC];
      float dx = x[s * 3 + 0] - x[d * 3 + 0];
      float dy = x[s * 3 + 1] - x[d * 3 + 1];
      float dz = x[s * 3 + 2] - x[d * 3 + 2];
      distS[w][lane] = dx * dx + dy * dy + dz * dz;
      dsh[w][lane] = d;
    }

    // (B) staging: sums Aes[s]+Aed[d] -> S[edge][n] (bf16), from prefetched G
    #pragma unroll
    for (int it = 0; it < 4; ++it){
      const int eg = q + 4 * it;
      float fa[8], fb[8];
      unp8(G[2 * it], fa); unp8(G[2 * it + 1], fb);
      union { short8 v; unsigned int u[4]; } sv;
      #pragma unroll
      for (int jj = 0; jj < 4; ++jj)
        sv.u[jj] = packtrunc(fa[2 * jj] + fb[2 * jj], fa[2 * jj + 1] + fb[2 * jj + 1]);
      *(short8*)(S + eg * 136 + m * 8) = sv.v;
    }

    // (C) tail B-frag (input^T): lane = edge m, k-slice q*8; k<16=ea, k==16=dist
    union { short8 v; unsigned int u[4]; } at;
    at.u[0] = at.u[1] = at.u[2] = at.u[3] = 0u;
    if (q < 2){
      at.u[0] = packtrunc(EA0.x, EA0.y); at.u[1] = packtrunc(EA0.z, EA0.w);
      at.u[2] = packtrunc(EA1.x, EA1.y); at.u[3] = packtrunc(EA1.z, EA1.w);
    } else if (q == 2){
      at.u[0] = __float_as_uint(distS[w][m]) >> 16;
    }

    // (D) issue NEXT tile's gathers + ea; then load indices for tile t+2
    #pragma unroll
    for (int it = 0; it < 4; ++it){
      G[2 * it]     = *(const uint4*)(Aes + (size_t)sN[it] * HD + m * 8);
      G[2 * it + 1] = *(const uint4*)(Aed + (size_t)dN[it] * HD + m * 8);
    }
    if (q < 2){
      EA0 = *(const float4*)(ea + (size_t)pmN * ED + q * 8);
      EA1 = *(const float4*)(ea + (size_t)pmN * ED + q * 8 + 4);
    }
    {
      const int en2 = min(tb + 2 * nwv, tiles - 1) << 4;
      #pragma unroll
      for (int it = 0; it < 4; ++it){
        const int eC = min(en2 + q + 4 * it, E - 1);
        sN[it] = ss[eC]; dN[it] = ddv[eC];
      }
      pmN = perm[min(en2 + m, E - 1)];
    }

    // (E) tail MFMA swapped: A = W1tail^T (rows n), B = at (cols edge).
    // C-init b64 from S[m][t*16+q*4], silu, pack, b64 write back.
    #pragma unroll
    for (int t = 0; t < 8; ++t){
      uint2 cv = *(const uint2*)(S + m * 136 + t * 16 + q * 4);
      float4v ci;
      ci[0] = unplo(cv.x); ci[1] = unphi(cv.x);
      ci[2] = unplo(cv.y); ci[3] = unphi(cv.y);
      short8 aB;
      if (q < 3) aB = *(const short8*)(Btl + (t * 16 + m) * 24 + q * 8);
      else { union { short8 v; unsigned int u[4]; } z; z.u[0]=z.u[1]=z.u[2]=z.u[3]=0u; aB = z.v; }
      float4v o = __builtin_amdgcn_mfma_f32_16x16x32_bf16(aB, at.v, ci, 0, 0, 0);
      uint2 ov;
      ov.x = packtrunc(siluf(o[0]), siluf(o[1]));
      ov.y = packtrunc(siluf(o[2]), siluf(o[3]));
      *(uint2*)(S + m * 136 + t * 16 + q * 4) = ov;
    }

    // (F) layer-2 MFMA swapped: A = W2^T, B = u^T (cols edge from S[m][k])
    float4v c2[8];
    #pragma unroll
    for (int t = 0; t < 8; ++t) c2[t] = (float4v){0.f, 0.f, 0.f, 0.f};
    #pragma unroll
    for (int step = 0; step < 4; ++step){
      short8 bU = *(const short8*)(S + m * 136 + step * 32 + q * 8);
      #pragma unroll
      for (int t = 0; t < 8; ++t){
        short8 aW = *(const short8*)(W2t + (size_t)(t * 16 + m) * 136 + step * 32 + q * 8);
        c2[t] = __builtin_amdgcn_mfma_f32_16x16x32_bf16(aW, bU, c2[t], 0, 0, 0);
      }
    }

    // (G) attention: per lane edge = m holds n-values {t*16+q*4+r}.
    float p = 0.f;
    #pragma unroll
    for (int t = 0; t < 8; ++t){
      float4 bv = *(const float4*)(b2l + t * 16 + q * 4);
      float4 wv = *(const float4*)(wal + t * 16 + q * 4);
      c2[t][0] += bv.x; c2[t][1] += bv.y; c2[t][2] += bv.z; c2[t][3] += bv.w;
      p = fmaf(c2[t][0], wv.x, p); p = fmaf(c2[t][1], wv.y, p);
      p = fmaf(c2[t][2], wv.z, p); p = fmaf(c2[t][3], wv.w, p);
    }
    p += __shfl_xor(p, 16); p += __shfl_xor(p, 32);
    const float att = 1.f / (1.f + __expf(-(p + attb)));
    #pragma unroll
    for (int t = 0; t < 8; ++t){
      uint2 ov;
      ov.x = packtrunc(att * c2[t][0], att * c2[t][1]);
      ov.y = packtrunc(att * c2[t][2], att * c2[t][3]);
      *(uint2*)(S + m * 136 + t * 16 + q * 4) = ov;
    }

    // (H) segmented f32 reduction over sorted dsts; one pk atomic per run
    __builtin_amdgcn_sched_barrier(0);
    unsigned int vv[16]; int dvr[16];
    #pragma unroll
    for (int eg = 0; eg < 16; ++eg){
      vv[eg]  = *(const unsigned int*)(S + eg * 136 + lane * 2);
      dvr[eg] = dsh[w][eg];
    }
    float a0 = 0.f, a1 = 0.f;
    int dp = dvr[0];
    #pragma unroll
    for (int eg = 0; eg < 16; ++eg){
      if (dvr[eg] != dp){                       // wave-uniform branch
        atomAddBF2(msg_agg + (size_t)dp * HD + lane * 2, packbf(a0, a1));
        a0 = a1 = 0.f; dp = dvr[eg];
      }
      if (e0 + eg < E){ a0 += unplo(vv[eg]); a1 += unphi(vv[eg]); }
    }
    atomAddBF2(msg_agg + (size_t)dp * HD + lane * 2, packbf(a0, a1));
  }
}

// ---------------------------------------------------------------------------
// Kernel 3: coord path over dst-SORTED edges. Same v4 treatment.
// ---------------------------------------------------------------------------
__global__ void __launch_bounds__(512, 4) k_edge_coord(
    const int* __restrict__ ss, const int* __restrict__ ddv,
    const int* __restrict__ perm,
    const float* __restrict__ x, const float* __restrict__ ea,
    const unsigned short* __restrict__ Axs, const unsigned short* __restrict__ Axd,
    const float* __restrict__ Wx_w1, const float* __restrict__ Wx_w2,
    const float* __restrict__ Wx_b2, const float* __restrict__ Wx_w3,
    float* __restrict__ xout, int E)
{
  __shared__ __align__(16) unsigned short W2t[128 * 136];   // 34816 B
  __shared__ __align__(16) unsigned short Btl[128 * 24];    // 6144 B  [n][k<16]
  __shared__ __align__(16) unsigned short Ssh[8][16 * 136]; // 34816 B
  __shared__ __align__(16) float b2l[128];                  // 512 B
  __shared__ __align__(16) float w3l[128];                  // 512 B
  __shared__ float xaux[8][16 * 4];                         // 2048 B
  __shared__ float xcS[8][16 * 4];                          // 2048 B
  __shared__ int   dsh[8][16];                              // 512 B
  // total 81408 B -> 2 blocks/CU

  const int tid = threadIdx.x;
  for (int i = tid; i < 128 * 128; i += 512){
    int col = i & 127, k = i >> 7;
    W2t[col * 136 + k] = f2b(Wx_w2[k * 128 + col]);
  }
  for (int i = tid; i < 128 * 24; i += 512){
    int col = i / 24, k = i % 24;
    Btl[col * 24 + k] = f2b(k < 16 ? Wx_w1[(256 + k) * 128 + col] : 0.f);
  }
  for (int i = tid; i < 128; i += 512){
    b2l[i] = Wx_b2[i];
    w3l[i] = Wx_w3[i];
  }
  __syncthreads();

  const int lane = tid & 63, w = tid >> 6;
  const int m = lane & 15, q = lane >> 4;

  unsigned short* S = Ssh[w];
  float* xa = xaux[w];
  float* xc = xcS[w];

  const int tiles = (E + 15) >> 4;
  const int wid = blockIdx.x * 8 + w;
  const int nwv = gridDim.x * 8;

  uint4 G[8];
  float4 EA0 = {0,0,0,0}, EA1 = {0,0,0,0};
  int sN[4], dN[4], pmN = 0;

  {
    const int e0 = wid << 4;
    int s0[4], d0[4];
    #pragma unroll
    for (int it = 0; it < 4; ++it){
      const int eC = min(e0 + q + 4 * it, E - 1);
      s0[it] = ss[eC]; d0[it] = ddv[eC];
    }
    #pragma unroll
    for (int it = 0; it < 4; ++it){
      G[2 * it]     = *(const uint4*)(Axs + (size_t)s0[it] * HD + m * 8);
      G[2 * it + 1] = *(const uint4*)(Axd + (size_t)d0[it] * HD + m * 8);
    }
    if (q < 2){
      const int pm0 = perm[min(e0 + m, E - 1)];
      EA0 = *(const float4*)(ea + (size_t)pm0 * ED + q * 8);
      EA1 = *(const float4*)(ea + (size_t)pm0 * ED + q * 8 + 4);
    }
    const int en0 = min(wid + nwv, tiles - 1) << 4;
    #pragma unroll
    for (int it = 0; it < 4; ++it){
      const int eC = min(en0 + q + 4 * it, E - 1);
      sN[it] = ss[eC]; dN[it] = ddv[eC];
    }
    pmN = perm[min(en0 + m, E - 1)];
  }

  for (int tb = wid; tb < tiles; tb += nwv){
    const int e0 = tb << 4;

    // (A) per-edge scalars
    if (lane < 16){
      int eC = min(e0 + lane, E - 1);
      int s = ss[eC], d = ddv[eC];
      float dx = x[s * 3 + 0] - x[d * 3 + 0];
      float dy = x[s * 3 + 1] - x[d * 3 + 1];
      float dz = x[s * 3 + 2] - x[d * 3 + 2];
      float dist = dx * dx + dy * dy + dz * dz;
      xa[lane * 4 + 0] = dx;
      xa[lane * 4 + 1] = dy;
      xa[lane * 4 + 2] = dz;
      xa[lane * 4 + 3] = 2.5f / (sqrtf(dist + 1e-8f) + 1.0f);
      dsh[w][lane] = d;
    }

    // (B) staging
    #pragma unroll
    for (int it = 0; it < 4; ++it){
      const int eg = q + 4 * it;
      float fa[8], fb[8];
      unp8(G[2 * it], fa); unp8(G[2 * it + 1], fb);
      union { short8 v; unsigned int u[4]; } sv;
      #pragma unroll
      for (int jj = 0; jj < 4; ++jj)
        sv.u[jj] = packtrunc(fa[2 * jj] + fb[2 * jj], fa[2 * jj + 1] + fb[2 * jj + 1]);
      *(short8*)(S + eg * 136 + m * 8) = sv.v;
    }

    // (C) tail B-frag (ea only)
    union { short8 v; unsigned int u[4]; } at;
    at.u[0] = at.u[1] = at.u[2] = at.u[3] = 0u;
    if (q < 2){
      at.u[0] = packtrunc(EA0.x, EA0.y); at.u[1] = packtrunc(EA0.z, EA0.w);
      at.u[2] = packtrunc(EA1.x, EA1.y); at.u[3] = packtrunc(EA1.z, EA1.w);
    }

    // (D) issue next tile's gathers + ea; load t+2 indices
    #pragma unroll
    for (int it = 0; it < 4; ++it){
      G[2 * it]     = *(const uint4*)(Axs + (size_t)sN[it] * HD + m * 8);
      G[2 * it + 1] = *(const uint4*)(Axd + (size_t)dN[it] * HD + m * 8);
    }
    if (q < 2){
      EA0 = *(const float4*)(ea + (size_t)pmN * ED + q * 8);
      EA1 = *(const float4*)(ea + (size_t)pmN * ED + q * 8 + 4);
    }
    {
      const int en2 = min(tb + 2 * nwv, tiles - 1) << 4;
      #pragma unroll
      for (int it = 0; it < 4; ++it){
        const int eC = min(en2 + q + 4 * it, E - 1);
        sN[it] = ss[eC]; dN[it] = ddv[eC];
      }
      pmN = perm[min(en2 + m, E - 1)];
    }

    // (E) tail MFMA swapped + silu
    #pragma unroll
    for (int t = 0; t < 8; ++t){
      uint2 cv = *(const uint2*)(S + m * 136 + t * 16 + q * 4);
      float4v ci;
      ci[0] = unplo(cv.x); ci[1] = unphi(cv.x);
      ci[2] = unplo(cv.y); ci[3] = unphi(cv.y);
      short8 aB;
      if (q < 2) aB = *(const short8*)(Btl + (t * 16 + m) * 24 + q * 8);
      else { union { short8 v; unsigned int u[4]; } z; z.u[0]=z.u[1]=z.u[2]=z.u[3]=0u; aB = z.v; }
      float4v o = __builtin_amdgcn_mfma_f32_16x16x32_bf16(aB, at.v, ci, 0, 0, 0);
      uint2 ov;
      ov.x = packtrunc(siluf(o[0]), siluf(o[1]));
      ov.y = packtrunc(siluf(o[2]), siluf(o[3]));
      *(uint2*)(S + m * 136 + t * 16 + q * 4) = ov;
    }

    // (F) layer-2 MFMA swapped
    float4v c2[8];
    #pragma unroll
    for (int t = 0; t < 8; ++t) c2[t] = (float4v){0.f, 0.f, 0.f, 0.f};
    #pragma unroll
    for (int step = 0; step < 4; ++step){
      short8 bU = *(const short8*)(S + m * 136 + step * 32 + q * 8);
      #pragma unroll
      for (int t = 0; t < 8; ++t){
        short8 aW = *(const short8*)(W2t + (size_t)(t * 16 + m) * 136 + step * 32 + q * 8);
        c2[t] = __builtin_amdgcn_mfma_f32_16x16x32_bf16(aW, bU, c2[t], 0, 0, 0);
      }
    }

    // (G) coord weight: per lane edge = m; 1 tanh/lane; 2-shfl reduce
    float p = 0.f;
    #pragma unroll
    for (int t = 0; t < 8; ++t){
      float4 bv = *(const float4*)(b2l + t * 16 + q * 4);
      float4 wv = *(const float4*)(w3l + t * 16 + q * 4);
      p = fmaf(siluf(c2[t][0] + bv.x), wv.x, p);
      p = fmaf(siluf(c2[t][1] + bv.y), wv.y, p);
      p = fmaf(siluf(c2[t][2] + bv.z), wv.z, p);
      p = fmaf(siluf(c2[t][3] + bv.w), wv.w, p);
    }
    p += __shfl_xor(p, 16); p += __shfl_xor(p, 32);
    {
      float sc = tanhf(p) * xa[m * 4 + 3];
      if (q < 3) xc[m * 4 + q] = xa[m * 4 + q] * sc;
    }

    // (H) segmented emit: lanes 0..2, one f32 atomic per same-dst run
    __builtin_amdgcn_sched_barrier(0);
    if (lane < 3){
      const int* dI = dsh[w];
      int dp = dI[0]; float acc = 0.f;
      #pragma unroll
      for (int eg = 0; eg < 16; ++eg){
        int dc = dI[eg];
        if (dc != dp){
          atomAddF(xout + (size_t)dp * 3 + lane, acc);
          acc = 0.f; dp = dc;
        }
        if (e0 + eg < E) acc += xc[eg * 4 + lane];
      }
      atomAddF(xout + (size_t)dp * 3 + lane, acc);
    }
  }
}

// ---------------------------------------------------------------------------
// Kernel 4: z2 = bf16( silu( zpre + msg @ Wh_w1[128:256] ) ) — msg bf16.
// ---------------------------------------------------------------------------
__global__ void __launch_bounds__(256) k_h1b2(
    const unsigned short* __restrict__ msg, const unsigned short* __restrict__ zpre,
    const float* __restrict__ Wh_w1, unsigned short* __restrict__ z2, int N)
{
  __shared__ unsigned short Wt[128 * 136];
  __shared__ unsigned short OutS[64 * 136];

  for (int i = threadIdx.x; i < 128 * 128; i += 256){
    int k = i >> 7, col = i & 127;
    Wt[col * 136 + k] = f2b(Wh_w1[(128 + k) * 128 + col]);
  }
  __syncthreads();

  const int lane = threadIdx.x & 63, w = threadIdx.x >> 6;
  const int m = lane & 15, q = lane >> 4;

  const int ntiles = (N + 63) >> 6;
  for (int tile = blockIdx.x; tile < ntiles; tile += gridDim.x){
    const int n0 = tile << 6;
    const int n = min(n0 + w * 16 + m, N - 1);

    short8 a[4];
    #pragma unroll
    for (int step = 0; step < 4; ++step)
      a[step] = *(const short8*)(msg + (size_t)n * 128 + step * 32 + q * 8);

    float4v acc[8];
    #pragma unroll
    for (int t = 0; t < 8; ++t) acc[t] = (float4v){0.f, 0.f, 0.f, 0.f};
    #pragma unroll
    for (int step = 0; step < 4; ++step){
      #pragma unroll
      for (int t = 0; t < 8; ++t){
        short8 b = *(const short8*)(Wt + (size_t)(t * 16 + m) * 136 + step * 32 + q * 8);
        acc[t] = __builtin_amdgcn_mfma_f32_16x16x32_bf16(a[step], b, acc[t], 0, 0, 0);
      }
    }

    #pragma unroll
    for (int t = 0; t < 8; ++t)
      #pragma unroll
      for (int r = 0; r < 4; ++r)
        OutS[(w * 16 + q * 4 + r) * 136 + t * 16 + m] = f2b(acc[t][r]);
    __syncthreads();
    for (int i = threadIdx.x; i < 64 * 16; i += 256){
      int node = i >> 4, seg = i & 15;
      int nn = n0 + node;
      if (nn < N){
        uint4 dv = *(const uint4*)(OutS + node * 136 + seg * 8);
        uint4 zv = *(const uint4*)(zpre + (size_t)nn * 128 + seg * 8);
        float fd[8], fz[8];
        unp8(dv, fd); unp8(zv, fz);
        uint4 ov;
        ov.x = packbf(siluf(fz[0] + fd[0]), siluf(fz[1] + fd[1]));
        ov.y = packbf(siluf(fz[2] + fd[2]), siluf(fz[3] + fd[3]));
        ov.z = packbf(siluf(fz[4] + fd[4]), siluf(fz[5] + fd[5]));
        ov.w = packbf(siluf(fz[6] + fd[6]), siluf(fz[7] + fd[7]));
        *(uint4*)(z2 + (size_t)nn * 128 + seg * 8) = ov;
      }
    }
    __syncthreads();
  }
}

// ---------------------------------------------------------------------------
// Kernel 5: hout = h + z2 @ Wh_w2 + Wh_b2
// ---------------------------------------------------------------------------
__global__ void __launch_bounds__(256) k_h22(
    const float* __restrict__ h, const unsigned short* __restrict__ z2,
    const float* __restrict__ Wh_w2, const float* __restrict__ Wh_b2,
    float* __restrict__ hout, int N)
{
  __shared__ unsigned short Wt[128 * 136];
  __shared__ float OutSf[64 * 132];

  for (int i = threadIdx.x; i < 128 * 128; i += 256){
    int k = i >> 7, col = i & 127;
    Wt[col * 136 + k] = f2b(Wh_w2[k * 128 + col]);
  }
  __syncthreads();

  const int lane = threadIdx.x & 63, w = threadIdx.x >> 6;
  const int m = lane & 15, q = lane >> 4;
  float bb[8];
  #pragma unroll
  for (int t = 0; t < 8; ++t) bb[t] = Wh_b2[t * 16 + m];

  const int ntiles = (N + 63) >> 6;
  for (int tile = blockIdx.x; tile < ntiles; tile += gridDim.x){
    const int n0 = tile << 6;
    const int n = min(n0 + w * 16 + m, N - 1);

    short8 a[4];
    #pragma unroll
    for (int step = 0; step < 4; ++step)
      a[step] = *(const short8*)(z2 + (size_t)n * 128 + step * 32 + q * 8);

    float4v acc[8];
    #pragma unroll
    for (int t = 0; t < 8; ++t) acc[t] = (float4v){0.f, 0.f, 0.f, 0.f};
    #pragma unroll
    for (int step = 0; step < 4; ++step){
      #pragma unroll
      for (int t = 0; t < 8; ++t){
        short8 b = *(const short8*)(Wt + (size_t)(t * 16 + m) * 136 + step * 32 + q * 8);
        acc[t] = __builtin_amdgcn_mfma_f32_16x16x32_bf16(a[step], b, acc[t], 0, 0, 0);
      }
    }

    #pragma unroll
    for (int t = 0; t < 8; ++t)
      #pragma unroll
      for (int r = 0; r < 4; ++r)
        OutSf[(w * 16 + q * 4 + r) * 132 + t * 16 + m] = acc[t][r] + bb[t];
    __syncthreads();
    for (int i = threadIdx.x; i < 64 * 32; i += 256){
      int node = i >> 5, seg = i & 31;
      int nn = n0 + node;
      if (nn < N){
        float4 dv = *(const float4*)(OutSf + node * 132 + seg * 4);
        float4 hv = *(const float4*)(h + (size_t)nn * 128 + seg * 4);
        float4 ov = {hv.x + dv.x, hv.y + dv.y, hv.z + dv.z, hv.w + dv.w};
        *(float4*)(hout + (size_t)nn * 128 + seg * 4) = ov;
      }
    }
    __syncthreads();
  }
}

extern "C" void kernel_launch(void* const* d_in, const int* in_sizes, int n_in,
                              void* d_out, int out_size, void* d_ws, size_t ws_size,
                              hipStream_t stream)
{
  const float* h      = (const float*)d_in[0];
  const float* x      = (const float*)d_in[1];
  const int*   ei     = (const int*)  d_in[2];
  const float* ea     = (const float*)d_in[3];
  const float* t_emb  = (const float*)d_in[4];
  const float* We_w1  = (const float*)d_in[5];
  const float* We_b1  = (const float*)d_in[6];
  const float* We_w2  = (const float*)d_in[7];
  const float* We_b2  = (const float*)d_in[8];
  const float* Watt_w = (const float*)d_in[9];
  const float* Watt_b = (const float*)d_in[10];
  const float* Wx_w1  = (const float*)d_in[11];
  const float* Wx_b1  = (const float*)d_in[12];
  const float* Wx_w2  = (const float*)d_in[13];
  const float* Wx_b2  = (const float*)d_in[14];
  const float* Wx_w3  = (const float*)d_in[15];
  const float* Wh_w1  = (const float*)d_in[16];
  const float* Wh_b1  = (const float*)d_in[17];
  const float* Wh_w2  = (const float*)d_in[18];
  const float* Wh_b2  = (const float*)d_in[19];

  const int N = in_sizes[0] / HD;
  const int E = in_sizes[2] / 2;

  char* ws = (char*)d_ws;
  unsigned short* Aes  = (unsigned short*)ws;  ws += (size_t)N * HD * 2;
  unsigned short* Aed  = (unsigned short*)ws;  ws += (size_t)N * HD * 2;
  unsigned short* Axs  = (unsigned short*)ws;  ws += (size_t)N * HD * 2;
  unsigned short* Axd  = (unsigned short*)ws;  ws += (size_t)N * HD * 2;
  unsigned short* zpre = (unsigned short*)ws;  ws += (size_t)N * HD * 2;
  unsigned short* z2   = (unsigned short*)ws;  ws += (size_t)N * HD * 2;
  unsigned short* msg_agg = (unsigned short*)ws; ws += (size_t)N * HD * 2;
  unsigned short* hb   = (unsigned short*)ws;  ws += (size_t)N * HD * 2;
  unsigned short* tb   = (unsigned short*)ws;  ws += (size_t)N * TD * 2;

  // Reuse hb (12.8MB) for sorted-edge arrays (7.2MB) AFTER k_pre2 consumed it;
  // reuse tb (3.2MB) for cnt/off (0.4MB). Stream order guarantees safety.
  int* ss_   = (int*)hb;
  int* ddv_  = ss_ + E;
  int* perm_ = ddv_ + E;
  int* cnt_  = (int*)tb;
  int* off_  = cnt_ + N;

  float* hout = (float*)d_out;
  float* xout = hout + (size_t)N * HD;

  hipMemsetAsync(msg_agg, 0, (size_t)N * HD * 2, stream);
  hipMemcpyAsync(xout, x, (size_t)N * 3 * 4, hipMemcpyDeviceToDevice, stream);

  k_cvt<<<400, 256, 0, stream>>>(h, hb, N * (HD / 8));
  k_cvt<<<100, 256, 0, stream>>>(t_emb, tb, N * (TD / 8));

  dim3 gP(192, 5);
  k_pre2<<<gP, 256, 0, stream>>>(hb, tb, We_w1, We_b1, Wx_w1, Wx_b1,
                                 Wh_w1, Wh_b1, Aes, Aed, Axs, Axd, zpre, N);

  // counting sort by dst (after k_pre2: hb/tb regions are free)
  hipMemsetAsync(cnt_, 0, (size_t)N * 4, stream);
  k_hist<<<512, 256, 0, stream>>>(ei, cnt_, E);
  k_scan<<<1, 1024, 0, stream>>>(cnt_, off_, N);
  k_scatter<<<512, 256, 0, stream>>>(ei, off_, ss_, ddv_, perm_, E);

  k_edge_msg<<<512, 512, 0, stream>>>(ss_, ddv_, perm_, x, ea, Aes, Aed,
                                      We_w1, We_w2, We_b2, Watt_w, Watt_b,
                                      msg_agg, E);
  k_edge_coord<<<512, 512, 0, stream>>>(ss_, ddv_, perm_, x, ea, Axs, Axd,
                                        Wx_w1, Wx_w2, Wx_b2, Wx_w3, xout, E);
  k_h1b2<<<512, 256, 0, stream>>>(msg_agg, zpre, Wh_w1, z2, N);
  k_h22<<<512, 256, 0, stream>>>(h, z2, Wh_w2, Wh_b2, hout, N);
}